// Round 1
// baseline (389.822 us; speedup 1.0000x reference)
//
#include <hip/hip_runtime.h>
#include <stdint.h>

// TripletRankingLoss: replicate JAX threefry2x32 (partitionable/foldlike mode)
// to reproduce the exact sampled pos/neg indices, then compute the margin loss.
//
// B=8192. Kernel 1: one block per anchor row; 2 threefry blocks per (i,j);
// u64-packed argmax (value<<32 | (0xFFFFFFFF-j)) gives jnp.argmax first-index
// tie-break. Kernel 2: deterministic final reduction.

#define B 8192
#define NTHREADS 256

struct TFOut { uint32_t a, b; };

__host__ __device__ constexpr uint32_t rotl32(uint32_t x, int r) {
    return (x << r) | (x >> (32 - r));
}

// Threefry-2x32, 20 rounds, exactly as jax/_src/prng.py threefry2x32.
__host__ __device__ constexpr TFOut threefry2x32(uint32_t k0, uint32_t k1,
                                                 uint32_t x0, uint32_t x1) {
    const uint32_t ks2 = k0 ^ k1 ^ 0x1BD11BDAu;
    x0 += k0; x1 += k1;
    // group 1: rotations 13,15,26,6
    x0 += x1; x1 = rotl32(x1, 13); x1 ^= x0;
    x0 += x1; x1 = rotl32(x1, 15); x1 ^= x0;
    x0 += x1; x1 = rotl32(x1, 26); x1 ^= x0;
    x0 += x1; x1 = rotl32(x1, 6);  x1 ^= x0;
    x0 += k1; x1 += ks2 + 1u;
    // group 2: 17,29,16,24
    x0 += x1; x1 = rotl32(x1, 17); x1 ^= x0;
    x0 += x1; x1 = rotl32(x1, 29); x1 ^= x0;
    x0 += x1; x1 = rotl32(x1, 16); x1 ^= x0;
    x0 += x1; x1 = rotl32(x1, 24); x1 ^= x0;
    x0 += ks2; x1 += k0 + 2u;
    // group 3: 13,15,26,6
    x0 += x1; x1 = rotl32(x1, 13); x1 ^= x0;
    x0 += x1; x1 = rotl32(x1, 15); x1 ^= x0;
    x0 += x1; x1 = rotl32(x1, 26); x1 ^= x0;
    x0 += x1; x1 = rotl32(x1, 6);  x1 ^= x0;
    x0 += k0; x1 += k1 + 3u;
    // group 4: 17,29,16,24
    x0 += x1; x1 = rotl32(x1, 17); x1 ^= x0;
    x0 += x1; x1 = rotl32(x1, 29); x1 ^= x0;
    x0 += x1; x1 = rotl32(x1, 16); x1 ^= x0;
    x0 += x1; x1 = rotl32(x1, 24); x1 ^= x0;
    x0 += k1; x1 += ks2 + 4u;
    // group 5: 13,15,26,6
    x0 += x1; x1 = rotl32(x1, 13); x1 ^= x0;
    x0 += x1; x1 = rotl32(x1, 15); x1 ^= x0;
    x0 += x1; x1 = rotl32(x1, 26); x1 ^= x0;
    x0 += x1; x1 = rotl32(x1, 6);  x1 ^= x0;
    x0 += ks2; x1 += k0 + 5u;
    return TFOut{x0, x1};
}

// jax.random.key(42) -> (0, 42). Partitionable split (foldlike):
// keys = threefry(key, counts=(hi,lo) of iota(2)); key[i] = both words of
// block (0, i). kp = keys[0], kn = keys[1].
constexpr TFOut KP = threefry2x32(0u, 42u, 0u, 0u);
constexpr TFOut KN = threefry2x32(0u, 42u, 0u, 1u);

__global__ __launch_bounds__(NTHREADS) void triplet_rows_kernel(
    const float* __restrict__ preds, const float* __restrict__ targets,
    float* __restrict__ loss_arr, float* __restrict__ valid_arr)
{
    __shared__ float t_sh[B];
    __shared__ unsigned long long redp[NTHREADS];
    __shared__ unsigned long long redn[NTHREADS];

    const int tid = threadIdx.x;
    const int row = blockIdx.x;

    // Stage all targets into LDS (32 KB), vectorized.
    const float4* t4 = reinterpret_cast<const float4*>(targets);
    float4* s4 = reinterpret_cast<float4*>(t_sh);
    for (int k = tid; k < B / 4; k += NTHREADS) s4[k] = t4[k];
    __syncthreads();

    const float ti = t_sh[row];
    const uint32_t base = (uint32_t)row * (uint32_t)B;

    // Packed argmax state: (bits23 << 32) | (0xFFFFFFFF - j).
    // Bigger bits wins; on tie, smaller j wins (jnp.argmax semantics).
    // 0 == "no valid entry" (any real entry has low word >= 0xFFFFE000).
    unsigned long long bestp = 0ull, bestn = 0ull;

    for (int j = tid; j < B; j += NTHREADS) {
        const float d = ti - t_sh[j];                 // diffs[i,j], exact fp32
        const uint32_t f = base + (uint32_t)j;        // flat index, hi word = 0
        // uniform(key,(B,B)) partitionable: bits = y0 ^ y1 of block (0, f);
        // u monotone in bits>>9 -> compare on bits>>9 directly.
        const TFOut rp = threefry2x32(KP.a, KP.b, 0u, f);
        const TFOut rn = threefry2x32(KN.a, KN.b, 0u, f);
        const uint32_t up = (rp.a ^ rp.b) >> 9;
        const uint32_t un = (rn.a ^ rn.b) >> 9;
        const unsigned long long tie = (unsigned long long)(0xFFFFFFFFu - (uint32_t)j);
        unsigned long long pp = ((unsigned long long)up << 32) | tie;
        unsigned long long pn = ((unsigned long long)un << 32) | tie;
        if (!(d < -0.1f)) pp = 0ull;  // pos_mask: diffs < -THRESH
        if (!(d >  0.1f)) pn = 0ull;  // neg_mask: diffs >  THRESH
        bestp = pp > bestp ? pp : bestp;
        bestn = pn > bestn ? pn : bestn;
    }

    redp[tid] = bestp;
    redn[tid] = bestn;
    __syncthreads();
    for (int s = NTHREADS / 2; s > 0; s >>= 1) {
        if (tid < s) {
            if (redp[tid + s] > redp[tid]) redp[tid] = redp[tid + s];
            if (redn[tid + s] > redn[tid]) redn[tid] = redn[tid + s];
        }
        __syncthreads();
    }

    if (tid == 0) {
        const unsigned long long bp = redp[0];
        const unsigned long long bn = redn[0];
        float loss = 0.0f, valid = 0.0f;
        if (bp != 0ull && bn != 0ull) {
            const int pj = (int)(0xFFFFFFFFu - (uint32_t)bp);
            const int nj = (int)(0xFFFFFFFFu - (uint32_t)bn);
            const float per = 0.5f - (preds[pj] - preds[nj]);  // MARGIN - (p_pos - p_neg)
            loss = per > 0.0f ? per : 0.0f;
            valid = 1.0f;
        }
        loss_arr[row] = loss;
        valid_arr[row] = valid;
    }
}

__global__ __launch_bounds__(NTHREADS) void finalize_kernel(
    const float* __restrict__ loss_arr, const float* __restrict__ valid_arr,
    float* __restrict__ out)
{
    __shared__ float sl[NTHREADS];
    __shared__ float sv[NTHREADS];
    float l = 0.0f, v = 0.0f;
    for (int k = threadIdx.x; k < B; k += NTHREADS) {
        l += loss_arr[k];
        v += valid_arr[k];
    }
    sl[threadIdx.x] = l;
    sv[threadIdx.x] = v;
    __syncthreads();
    for (int s = NTHREADS / 2; s > 0; s >>= 1) {
        if (threadIdx.x < s) {
            sl[threadIdx.x] += sl[threadIdx.x + s];
            sv[threadIdx.x] += sv[threadIdx.x + s];
        }
        __syncthreads();
    }
    if (threadIdx.x == 0) {
        const float num = sv[0];
        out[0] = (num > 0.0f) ? (sl[0] / fmaxf(num, 1.0f)) : 0.0f;
    }
}

extern "C" void kernel_launch(void* const* d_in, const int* in_sizes, int n_in,
                              void* d_out, int out_size, void* d_ws, size_t ws_size,
                              hipStream_t stream) {
    const float* preds   = (const float*)d_in[0];
    const float* targets = (const float*)d_in[1];
    float* loss_arr  = (float*)d_ws;       // [B]
    float* valid_arr = loss_arr + B;       // [B]
    triplet_rows_kernel<<<B, NTHREADS, 0, stream>>>(preds, targets, loss_arr, valid_arr);
    finalize_kernel<<<1, NTHREADS, 0, stream>>>(loss_arr, valid_arr, (float*)d_out);
}

// Round 2
// 198.073 us; speedup vs baseline: 1.9681x; 1.9681x over previous
//
#include <hip/hip_runtime.h>
#include <stdint.h>

// TripletRankingLoss, bit-exact JAX threefry replication + candidate compaction.
//
// R1 baseline (390 us, VALUBusy 97%): 2 threefry per (i,j) over all B^2 pairs.
// R2: counting-sort targets into 1024 bins; per row scan only the candidate
// prefix (neg: tj < ti-0.1) and suffix (pos: tj > ti+0.1) -> 0.81*B^2 single
// threefry evals instead of 2*B^2. Exact fp32 predicate re-checked per element
// (bin cut has 1e-4 conservative margin), so results stay bit-exact.

#define B 8192
#define K 1024          // bins for counting sort
#define NT 256          // threads in rows kernel
#define RPB 4           // rows per block (amortize LDS staging)

struct TFOut { uint32_t a, b; };

__host__ __device__ constexpr uint32_t rotl32(uint32_t x, int r) {
    return (x << r) | (x >> (32 - r));
}

// Threefry-2x32, 20 rounds, exactly as jax/_src/prng.py threefry2x32.
__host__ __device__ constexpr TFOut threefry2x32(uint32_t k0, uint32_t k1,
                                                 uint32_t x0, uint32_t x1) {
    const uint32_t ks2 = k0 ^ k1 ^ 0x1BD11BDAu;
    x0 += k0; x1 += k1;
    x0 += x1; x1 = rotl32(x1, 13); x1 ^= x0;
    x0 += x1; x1 = rotl32(x1, 15); x1 ^= x0;
    x0 += x1; x1 = rotl32(x1, 26); x1 ^= x0;
    x0 += x1; x1 = rotl32(x1, 6);  x1 ^= x0;
    x0 += k1; x1 += ks2 + 1u;
    x0 += x1; x1 = rotl32(x1, 17); x1 ^= x0;
    x0 += x1; x1 = rotl32(x1, 29); x1 ^= x0;
    x0 += x1; x1 = rotl32(x1, 16); x1 ^= x0;
    x0 += x1; x1 = rotl32(x1, 24); x1 ^= x0;
    x0 += ks2; x1 += k0 + 2u;
    x0 += x1; x1 = rotl32(x1, 13); x1 ^= x0;
    x0 += x1; x1 = rotl32(x1, 15); x1 ^= x0;
    x0 += x1; x1 = rotl32(x1, 26); x1 ^= x0;
    x0 += x1; x1 = rotl32(x1, 6);  x1 ^= x0;
    x0 += k0; x1 += k1 + 3u;
    x0 += x1; x1 = rotl32(x1, 17); x1 ^= x0;
    x0 += x1; x1 = rotl32(x1, 29); x1 ^= x0;
    x0 += x1; x1 = rotl32(x1, 16); x1 ^= x0;
    x0 += x1; x1 = rotl32(x1, 24); x1 ^= x0;
    x0 += k1; x1 += ks2 + 4u;
    x0 += x1; x1 = rotl32(x1, 13); x1 ^= x0;
    x0 += x1; x1 = rotl32(x1, 15); x1 ^= x0;
    x0 += x1; x1 = rotl32(x1, 26); x1 ^= x0;
    x0 += x1; x1 = rotl32(x1, 6);  x1 ^= x0;
    x0 += ks2; x1 += k0 + 5u;
    return TFOut{x0, x1};
}

// jax.random.key(42) -> (0,42); partitionable split: kp = block(0,0), kn = block(0,1).
constexpr TFOut KP = threefry2x32(0u, 42u, 0u, 0u);
constexpr TFOut KN = threefry2x32(0u, 42u, 0u, 1u);

// ---------------- Kernel A: counting sort of targets into K bins -------------
__global__ __launch_bounds__(1024) void sort_kernel(
    const float* __restrict__ targets,
    float* __restrict__ sorted_t, uint16_t* __restrict__ sorted_idx,
    int* __restrict__ bin_start_g)
{
    __shared__ int hist[K];
    __shared__ int scan_a[K];
    __shared__ int cursor[K];
    const int tid = threadIdx.x;

    hist[tid] = 0;
    __syncthreads();

    float v[B / 1024];
    int   bn[B / 1024];
    for (int i = 0; i < B / 1024; ++i) {
        const int e = tid + i * 1024;
        v[i] = targets[e];
        int b = (int)(v[i] * (float)K);
        b = b < 0 ? 0 : (b > K - 1 ? K - 1 : b);
        bn[i] = b;
        atomicAdd(&hist[b], 1);
    }
    __syncthreads();

    // Inclusive Hillis-Steele scan over K bins (1 bin per thread).
    const int cnt = hist[tid];
    scan_a[tid] = cnt;
    __syncthreads();
    for (int off = 1; off < K; off <<= 1) {
        const int y = scan_a[tid];
        const int z = (tid >= off) ? scan_a[tid - off] : 0;
        __syncthreads();
        scan_a[tid] = y + z;
        __syncthreads();
    }
    const int incl = scan_a[tid];
    cursor[tid] = incl - cnt;          // exclusive prefix
    bin_start_g[tid + 1] = incl;
    if (tid == 0) bin_start_g[0] = 0;
    __syncthreads();

    // Scatter (within-bin order arbitrary; exact predicate re-check later).
    for (int i = 0; i < B / 1024; ++i) {
        const int e = tid + i * 1024;
        const int p = atomicAdd(&cursor[bn[i]], 1);
        sorted_t[p]   = v[i];
        sorted_idx[p] = (uint16_t)e;
    }
}

// ---------------- Kernel B: per-row candidate scan + argmax ------------------
__global__ __launch_bounds__(NT) void rows_kernel(
    const float* __restrict__ preds, const float* __restrict__ targets,
    const float* __restrict__ sorted_t_g, const uint16_t* __restrict__ sorted_idx_g,
    const int* __restrict__ bin_start, float* __restrict__ loss_arr,
    float* __restrict__ valid_arr)
{
    __shared__ float    st[B];       // 32 KB
    __shared__ uint16_t sidx[B];     // 16 KB
    __shared__ unsigned long long redp[NT];  // 2 KB
    __shared__ unsigned long long redn[NT];  // 2 KB

    const int tid = threadIdx.x;

    // Stage bin-sorted arrays into LDS, vectorized.
    {
        const float4* t4 = reinterpret_cast<const float4*>(sorted_t_g);
        float4* s4 = reinterpret_cast<float4*>(st);
        for (int k = tid; k < B / 4; k += NT) s4[k] = t4[k];
        const uint4* i4 = reinterpret_cast<const uint4*>(sorted_idx_g);
        uint4* d4 = reinterpret_cast<uint4*>(sidx);
        for (int k = tid; k < B / 8; k += NT) d4[k] = i4[k];
    }
    __syncthreads();

    for (int r = 0; r < RPB; ++r) {
        const int row = blockIdx.x * RPB + r;
        const float ti = targets[row];
        const uint32_t base = (uint32_t)row * (uint32_t)B;

        // Candidate ranges (conservative by 1e-4 >> fp32 ulp slack of the
        // exact predicate fl(ti - tj) <> +/-0.1f).
        int endn;   // neg candidates: s in [0, endn)
        {
            const float cutn = ti - 0.1f + 1e-4f;
            if (cutn <= 0.0f) endn = 0;
            else {
                int b2 = (int)(cutn * (float)K);
                b2 = b2 > K - 1 ? K - 1 : b2;
                endn = bin_start[b2 + 1];
            }
        }
        int startp; // pos candidates: s in [startp, B)
        {
            const float cutp = ti + 0.1f - 1e-4f;
            if (cutp >= 1.0f) startp = B;
            else {
                int b = (int)(cutp * (float)K);
                b = b < 0 ? 0 : (b > K - 1 ? K - 1 : b);
                startp = bin_start[b];
            }
        }

        // Packed argmax: (bits23 << 32) | (0xFFFFFFFF - j). Bigger bits wins;
        // tie -> smaller original j (jnp.argmax first-index). 0 == invalid.
        auto elem_neg = [&](int s) -> unsigned long long {
            const float tj = st[s];
            const uint32_t j = sidx[s];
            const float d = ti - tj;
            const TFOut rr = threefry2x32(KN.a, KN.b, 0u, base + j);
            const uint32_t u = (rr.a ^ rr.b) >> 9;
            unsigned long long p =
                ((unsigned long long)u << 32) | (unsigned long long)(0xFFFFFFFFu - j);
            return (d > 0.1f) ? p : 0ull;
        };
        auto elem_pos = [&](int s) -> unsigned long long {
            const float tj = st[s];
            const uint32_t j = sidx[s];
            const float d = ti - tj;
            const TFOut rr = threefry2x32(KP.a, KP.b, 0u, base + j);
            const uint32_t u = (rr.a ^ rr.b) >> 9;
            unsigned long long p =
                ((unsigned long long)u << 32) | (unsigned long long)(0xFFFFFFFFu - j);
            return (d < -0.1f) ? p : 0ull;
        };

        // Neg scan, unroll-2 for ILP on the serial threefry chain.
        unsigned long long n0 = 0ull, n1 = 0ull;
        {
            int s = tid;
            for (; s + NT < endn; s += 2 * NT) {
                const unsigned long long a = elem_neg(s);
                const unsigned long long b = elem_neg(s + NT);
                n0 = a > n0 ? a : n0;
                n1 = b > n1 ? b : n1;
            }
            for (; s < endn; s += NT) {
                const unsigned long long a = elem_neg(s);
                n0 = a > n0 ? a : n0;
            }
        }
        // Pos scan.
        unsigned long long p0 = 0ull, p1 = 0ull;
        {
            int s = startp + tid;
            for (; s + NT < B; s += 2 * NT) {
                const unsigned long long a = elem_pos(s);
                const unsigned long long b = elem_pos(s + NT);
                p0 = a > p0 ? a : p0;
                p1 = b > p1 ? b : p1;
            }
            for (; s < B; s += NT) {
                const unsigned long long a = elem_pos(s);
                p0 = a > p0 ? a : p0;
            }
        }

        redn[tid] = n0 > n1 ? n0 : n1;
        redp[tid] = p0 > p1 ? p0 : p1;
        __syncthreads();
        for (int s2 = NT / 2; s2 > 0; s2 >>= 1) {
            if (tid < s2) {
                if (redp[tid + s2] > redp[tid]) redp[tid] = redp[tid + s2];
                if (redn[tid + s2] > redn[tid]) redn[tid] = redn[tid + s2];
            }
            __syncthreads();
        }

        if (tid == 0) {
            const unsigned long long bp = redp[0];
            const unsigned long long bn2 = redn[0];
            float loss = 0.0f, valid = 0.0f;
            if (bp != 0ull && bn2 != 0ull) {
                const int pj = (int)(0xFFFFFFFFu - (uint32_t)bp);
                const int nj = (int)(0xFFFFFFFFu - (uint32_t)bn2);
                const float per = 0.5f - (preds[pj] - preds[nj]);
                loss = per > 0.0f ? per : 0.0f;
                valid = 1.0f;
            }
            loss_arr[row] = loss;
            valid_arr[row] = valid;
        }
        __syncthreads();
    }
}

// ---------------- Kernel C: final deterministic reduction --------------------
__global__ __launch_bounds__(NT) void finalize_kernel(
    const float* __restrict__ loss_arr, const float* __restrict__ valid_arr,
    float* __restrict__ out)
{
    __shared__ float sl[NT];
    __shared__ float sv[NT];
    float l = 0.0f, v = 0.0f;
    for (int k = threadIdx.x; k < B; k += NT) {
        l += loss_arr[k];
        v += valid_arr[k];
    }
    sl[threadIdx.x] = l;
    sv[threadIdx.x] = v;
    __syncthreads();
    for (int s = NT / 2; s > 0; s >>= 1) {
        if (threadIdx.x < s) {
            sl[threadIdx.x] += sl[threadIdx.x + s];
            sv[threadIdx.x] += sv[threadIdx.x + s];
        }
        __syncthreads();
    }
    if (threadIdx.x == 0) {
        const float num = sv[0];
        out[0] = (num > 0.0f) ? (sl[0] / fmaxf(num, 1.0f)) : 0.0f;
    }
}

extern "C" void kernel_launch(void* const* d_in, const int* in_sizes, int n_in,
                              void* d_out, int out_size, void* d_ws, size_t ws_size,
                              hipStream_t stream) {
    const float* preds   = (const float*)d_in[0];
    const float* targets = (const float*)d_in[1];

    float* ws = (float*)d_ws;
    float*    sorted_t   = ws;                            // B floats
    uint16_t* sorted_idx = (uint16_t*)(ws + B);           // B u16 = B/2 floats
    int*      bin_start  = (int*)(ws + B + B / 2);        // K+1 ints (reserve 2048)
    float*    loss_arr   = ws + B + B / 2 + 2048;         // B floats
    float*    valid_arr  = loss_arr + B;                  // B floats

    sort_kernel<<<1, 1024, 0, stream>>>(targets, sorted_t, sorted_idx, bin_start);
    rows_kernel<<<B / RPB, NT, 0, stream>>>(preds, targets, sorted_t, sorted_idx,
                                            bin_start, loss_arr, valid_arr);
    finalize_kernel<<<1, NT, 0, stream>>>(loss_arr, valid_arr, (float*)d_out);
}

// Round 3
// 189.287 us; speedup vs baseline: 2.0594x; 1.0464x over previous
//
#include <hip/hip_runtime.h>
#include <stdint.h>

// TripletRankingLoss, bit-exact JAX threefry (partitionable) replication.
// R3: bin-sorted candidate ranges with boundary-bin-only exact predicate;
// 1 row per wave (no per-row barriers); no LDS staging (sorted arrays are
// L1-resident: 48 KB total); finalize fused via atomics + last-block-out;
// shfl-scan sort. Floor: 0.81*B^2 threefry evals ~54 us of int-VALU.

#define B 8192
#define K 1024

struct TFOut { uint32_t a, b; };

__host__ __device__ constexpr uint32_t rotl32(uint32_t x, int r) {
    return (x << r) | (x >> (32 - r));
}

// Full Threefry-2x32 (20 rounds), exactly as jax/_src/prng.py — used at
// compile time to derive the split keys.
__host__ __device__ constexpr TFOut threefry_full(uint32_t k0, uint32_t k1,
                                                  uint32_t x0, uint32_t x1) {
    const uint32_t ks2 = k0 ^ k1 ^ 0x1BD11BDAu;
    x0 += k0; x1 += k1;
    x0 += x1; x1 = rotl32(x1,13); x1 ^= x0;
    x0 += x1; x1 = rotl32(x1,15); x1 ^= x0;
    x0 += x1; x1 = rotl32(x1,26); x1 ^= x0;
    x0 += x1; x1 = rotl32(x1,6);  x1 ^= x0;
    x0 += k1; x1 += ks2 + 1u;
    x0 += x1; x1 = rotl32(x1,17); x1 ^= x0;
    x0 += x1; x1 = rotl32(x1,29); x1 ^= x0;
    x0 += x1; x1 = rotl32(x1,16); x1 ^= x0;
    x0 += x1; x1 = rotl32(x1,24); x1 ^= x0;
    x0 += ks2; x1 += k0 + 2u;
    x0 += x1; x1 = rotl32(x1,13); x1 ^= x0;
    x0 += x1; x1 = rotl32(x1,15); x1 ^= x0;
    x0 += x1; x1 = rotl32(x1,26); x1 ^= x0;
    x0 += x1; x1 = rotl32(x1,6);  x1 ^= x0;
    x0 += k0; x1 += k1 + 3u;
    x0 += x1; x1 = rotl32(x1,17); x1 ^= x0;
    x0 += x1; x1 = rotl32(x1,29); x1 ^= x0;
    x0 += x1; x1 = rotl32(x1,16); x1 ^= x0;
    x0 += x1; x1 = rotl32(x1,24); x1 ^= x0;
    x0 += k1; x1 += ks2 + 4u;
    x0 += x1; x1 = rotl32(x1,13); x1 ^= x0;
    x0 += x1; x1 = rotl32(x1,15); x1 ^= x0;
    x0 += x1; x1 = rotl32(x1,26); x1 ^= x0;
    x0 += x1; x1 = rotl32(x1,6);  x1 ^= x0;
    x0 += ks2; x1 += k0 + 5u;
    return TFOut{x0, x1};
}

// jax.random.key(42) -> (0,42); partitionable split: kp=block(0,0), kn=block(0,1).
constexpr TFOut KP = threefry_full(0u, 42u, 0u, 0u);
constexpr TFOut KN = threefry_full(0u, 42u, 0u, 1u);

// Device-fast threefry: x0=0 implicit, keys compile-time, caller passes
// x1 pre-keyed (= f + K1). alignbit guarantees 1-inst rotates.
template<uint32_t TK0, uint32_t TK1>
__device__ __forceinline__ uint32_t tf_bits(uint32_t x1) {
    constexpr uint32_t KS2 = TK0 ^ TK1 ^ 0x1BD11BDAu;
    uint32_t x0 = TK0;
#define RND(r) x0 += x1; x1 = __builtin_amdgcn_alignbit(x1, x1, 32 - (r)); x1 ^= x0;
    RND(13) RND(15) RND(26) RND(6)
    x0 += TK1; x1 += KS2 + 1u;
    RND(17) RND(29) RND(16) RND(24)
    x0 += KS2; x1 += TK0 + 2u;
    RND(13) RND(15) RND(26) RND(6)
    x0 += TK0; x1 += TK1 + 3u;
    RND(17) RND(29) RND(16) RND(24)
    x0 += TK1; x1 += KS2 + 4u;
    RND(13) RND(15) RND(26) RND(6)
    x0 += KS2; x1 += TK0 + 5u;
#undef RND
    return x0 ^ x1;
}

// ------------- Kernel A: counting sort into K bins + accumulator init -------
__global__ __launch_bounds__(1024) void sort_kernel(
    const float* __restrict__ targets,
    float* __restrict__ sorted_t, uint16_t* __restrict__ sorted_idx,
    int* __restrict__ bin_start, float* __restrict__ loss_sum,
    float* __restrict__ valid_sum, unsigned int* __restrict__ done)
{
    __shared__ int hist[K];
    __shared__ int wsum[16];
    __shared__ int cursor[K];
    const int tid = threadIdx.x;

    hist[tid] = 0;
    if (tid == 0) { *loss_sum = 0.0f; *valid_sum = 0.0f; *done = 0u; }
    __syncthreads();

    float v[B / 1024];
    int   bnum[B / 1024];
    for (int i = 0; i < B / 1024; ++i) {
        const int e = tid + i * 1024;
        v[i] = targets[e];
        int b = (int)(v[i] * (float)K);
        b = b < 0 ? 0 : (b > K - 1 ? K - 1 : b);
        bnum[i] = b;
        atomicAdd(&hist[b], 1);
    }
    __syncthreads();

    // shfl-based inclusive scan: 64-lane scans + 16-wave-sum scan (3 barriers).
    const int cnt  = hist[tid];
    const int lane = tid & 63;
    const int wv   = tid >> 6;
    int incl = cnt;
    for (int d = 1; d < 64; d <<= 1) {
        const int o = __shfl_up(incl, d, 64);
        if (lane >= d) incl += o;
    }
    if (lane == 63) wsum[wv] = incl;
    __syncthreads();
    if (tid < 16) {
        int wincl = wsum[tid];
        for (int d = 1; d < 16; d <<= 1) {
            const int o = __shfl_up(wincl, d, 64);
            if (tid >= d) wincl += o;
        }
        wsum[tid] = wincl;
    }
    __syncthreads();
    incl += (wv > 0) ? wsum[wv - 1] : 0;
    bin_start[tid + 1] = incl;
    if (tid == 0) bin_start[0] = 0;
    cursor[tid] = incl - cnt;
    __syncthreads();

    for (int i = 0; i < B / 1024; ++i) {
        const int e = tid + i * 1024;
        const int p = atomicAdd(&cursor[bnum[i]], 1);
        sorted_t[p]   = v[i];
        sorted_idx[p] = (uint16_t)e;
    }
}

// ------------- Kernel B: per-wave row scan + fused finalize -----------------
__global__ __launch_bounds__(256) void rows_kernel(
    const float* __restrict__ preds, const float* __restrict__ targets,
    const float* __restrict__ sorted_t, const uint16_t* __restrict__ sorted_idx,
    const int* __restrict__ bin_start,
    float* __restrict__ loss_sum, float* __restrict__ valid_sum,
    unsigned int* __restrict__ done, float* __restrict__ out)
{
    __shared__ float sl[4], sv[4];
    const int lane = threadIdx.x & 63;
    const int wv   = threadIdx.x >> 6;
    const int row  = (blockIdx.x << 2) + wv;

    const float ti = targets[row];
    const uint32_t base = (uint32_t)row << 13;   // row * B

    // Candidate ranges from bins. Interior bins are decidable from the cut
    // (1e-4 margin >> all fp32 rounding slack); only boundary-zone elements
    // [un_end,cn_end) / [cp_beg,up_beg) get the exact fp32 predicate.
    const float cutn = ti - 0.1f;
    int bl = (int)floorf((cutn - 1e-4f) * (float)K);
    int bh = (int)floorf((cutn + 1e-4f) * (float)K) + 1;
    bl = bl < 0 ? 0 : (bl > K ? K : bl);
    bh = bh < 0 ? 0 : (bh > K ? K : bh);
    const int un_end = bin_start[bl];   // unchecked neg: [0, un_end)
    const int cn_end = bin_start[bh];   // checked  neg: [un_end, cn_end)

    const float cutp = ti + 0.1f;
    int pl = (int)floorf((cutp - 1e-4f) * (float)K);
    int ph = (int)floorf((cutp + 1e-4f) * (float)K) + 1;
    pl = pl < 0 ? 0 : (pl > K ? K : pl);
    ph = ph < 0 ? 0 : (ph > K ? K : ph);
    const int cp_beg = bin_start[pl];   // checked  pos: [cp_beg, up_beg)
    const int up_beg = bin_start[ph];   // unchecked pos: [up_beg, B)

    const uint32_t bkn = base + KN.b;   // pre-keyed counter bases
    const uint32_t bkp = base + KP.b;

    // Packed argmax key: (bits23 << 32) | ~j. Bigger bits wins; tie -> bigger
    // ~j = smaller j (jnp.argmax first-index). 0 == invalid sentinel.
    uint64_t n0 = 0, n1 = 0;
    {
        int s = lane;
        for (; s + 64 < un_end; s += 128) {
            const uint32_t j0 = sorted_idx[s];
            const uint32_t j1 = sorted_idx[s + 64];
            const uint32_t h0 = tf_bits<KN.a, KN.b>(j0 + bkn) >> 9;
            const uint32_t h1 = tf_bits<KN.a, KN.b>(j1 + bkn) >> 9;
            const uint64_t c0 = ((uint64_t)h0 << 32) | (~j0);
            const uint64_t c1 = ((uint64_t)h1 << 32) | (~j1);
            n0 = c0 > n0 ? c0 : n0;
            n1 = c1 > n1 ? c1 : n1;
        }
        for (; s < un_end; s += 64) {
            const uint32_t j0 = sorted_idx[s];
            const uint32_t h0 = tf_bits<KN.a, KN.b>(j0 + bkn) >> 9;
            const uint64_t c0 = ((uint64_t)h0 << 32) | (~j0);
            n0 = c0 > n0 ? c0 : n0;
        }
        for (s = un_end + lane; s < cn_end; s += 64) {   // boundary zone
            const float tj = sorted_t[s];
            const uint32_t j0 = sorted_idx[s];
            const uint32_t h0 = tf_bits<KN.a, KN.b>(j0 + bkn) >> 9;
            const uint64_t c0 = ((uint64_t)h0 << 32) | (~j0);
            if (ti - tj > 0.1f) n0 = c0 > n0 ? c0 : n0;  // exact predicate
        }
    }
    uint64_t bestn = n0 > n1 ? n0 : n1;

    uint64_t p0 = 0, p1 = 0;
    {
        int s = up_beg + lane;
        for (; s + 64 < B; s += 128) {
            const uint32_t j0 = sorted_idx[s];
            const uint32_t j1 = sorted_idx[s + 64];
            const uint32_t h0 = tf_bits<KP.a, KP.b>(j0 + bkp) >> 9;
            const uint32_t h1 = tf_bits<KP.a, KP.b>(j1 + bkp) >> 9;
            const uint64_t c0 = ((uint64_t)h0 << 32) | (~j0);
            const uint64_t c1 = ((uint64_t)h1 << 32) | (~j1);
            p0 = c0 > p0 ? c0 : p0;
            p1 = c1 > p1 ? c1 : p1;
        }
        for (; s < B; s += 64) {
            const uint32_t j0 = sorted_idx[s];
            const uint32_t h0 = tf_bits<KP.a, KP.b>(j0 + bkp) >> 9;
            const uint64_t c0 = ((uint64_t)h0 << 32) | (~j0);
            p0 = c0 > p0 ? c0 : p0;
        }
        for (s = cp_beg + lane; s < up_beg; s += 64) {   // boundary zone
            const float tj = sorted_t[s];
            const uint32_t j0 = sorted_idx[s];
            const uint32_t h0 = tf_bits<KP.a, KP.b>(j0 + bkp) >> 9;
            const uint64_t c0 = ((uint64_t)h0 << 32) | (~j0);
            if (ti - tj < -0.1f) p0 = c0 > p0 ? c0 : p0; // exact predicate
        }
    }
    uint64_t bestp = p0 > p1 ? p0 : p1;

    // In-wave u64-max reduction (no barriers).
    for (int off = 32; off > 0; off >>= 1) {
        const uint64_t on = (uint64_t)__shfl_down((unsigned long long)bestn, off, 64);
        const uint64_t op = (uint64_t)__shfl_down((unsigned long long)bestp, off, 64);
        bestn = on > bestn ? on : bestn;
        bestp = op > bestp ? op : bestp;
    }

    if (lane == 0) {
        float loss = 0.0f, valid = 0.0f;
        if (bestn != 0 && bestp != 0) {
            const int nj = (int)(~(uint32_t)bestn);
            const int pj = (int)(~(uint32_t)bestp);
            const float per = 0.5f - (preds[pj] - preds[nj]);
            loss = per > 0.0f ? per : 0.0f;
            valid = 1.0f;
        }
        sl[wv] = loss; sv[wv] = valid;
    }
    __syncthreads();
    if (threadIdx.x == 0) {
        atomicAdd(loss_sum,  sl[0] + sl[1] + sl[2] + sl[3]);
        atomicAdd(valid_sum, sv[0] + sv[1] + sv[2] + sv[3]);
        __threadfence();
        const unsigned int old = atomicAdd(done, 1u);
        if (old == gridDim.x - 1u) {          // last block finalizes
            const float ls = atomicAdd(loss_sum, 0.0f);
            const float vs = atomicAdd(valid_sum, 0.0f);
            out[0] = vs > 0.0f ? ls / fmaxf(vs, 1.0f) : 0.0f;
        }
    }
}

extern "C" void kernel_launch(void* const* d_in, const int* in_sizes, int n_in,
                              void* d_out, int out_size, void* d_ws, size_t ws_size,
                              hipStream_t stream) {
    const float* preds   = (const float*)d_in[0];
    const float* targets = (const float*)d_in[1];

    float* ws = (float*)d_ws;
    float*        sorted_t   = ws;                       // B floats
    uint16_t*     sorted_idx = (uint16_t*)(ws + B);      // B u16
    int*          bin_start  = (int*)(ws + B + B / 2);   // K+1 ints
    float*        loss_sum   = ws + B + B / 2 + 1536;
    float*        valid_sum  = loss_sum + 1;
    unsigned int* done       = (unsigned int*)(loss_sum + 2);

    sort_kernel<<<1, 1024, 0, stream>>>(targets, sorted_t, sorted_idx, bin_start,
                                        loss_sum, valid_sum, done);
    rows_kernel<<<B / 4, 256, 0, stream>>>(preds, targets, sorted_t, sorted_idx,
                                           bin_start, loss_sum, valid_sum, done,
                                           (float*)d_out);
}

// Round 4
// 180.170 us; speedup vs baseline: 2.1636x; 1.0506x over previous
//
#include <hip/hip_runtime.h>
#include <stdint.h>

// TripletRankingLoss, bit-exact-to-~1e-4 JAX threefry (partitionable) replication.
// R4: software-pipelined index loads (unroll-4 + preload-next-group) to kill
// vmcnt stalls; u32 (h>>9, j) accumulators with exact 23-bit compare and
// j tie-break at merge/reduce (JAX first-index semantics except same-lane
// same-stream 23-bit ties: ~0.1 rows/run, E[err]~3e-5). Floor ~59 us issue.

#define B 8192
#define K 1024

struct TFOut { uint32_t a, b; };

__host__ __device__ constexpr uint32_t rotl32(uint32_t x, int r) {
    return (x << r) | (x >> (32 - r));
}

// Full Threefry-2x32 (20 rounds), exactly as jax/_src/prng.py — compile-time
// only, to derive the split keys.
__host__ __device__ constexpr TFOut threefry_full(uint32_t k0, uint32_t k1,
                                                  uint32_t x0, uint32_t x1) {
    const uint32_t ks2 = k0 ^ k1 ^ 0x1BD11BDAu;
    x0 += k0; x1 += k1;
    x0 += x1; x1 = rotl32(x1,13); x1 ^= x0;
    x0 += x1; x1 = rotl32(x1,15); x1 ^= x0;
    x0 += x1; x1 = rotl32(x1,26); x1 ^= x0;
    x0 += x1; x1 = rotl32(x1,6);  x1 ^= x0;
    x0 += k1; x1 += ks2 + 1u;
    x0 += x1; x1 = rotl32(x1,17); x1 ^= x0;
    x0 += x1; x1 = rotl32(x1,29); x1 ^= x0;
    x0 += x1; x1 = rotl32(x1,16); x1 ^= x0;
    x0 += x1; x1 = rotl32(x1,24); x1 ^= x0;
    x0 += ks2; x1 += k0 + 2u;
    x0 += x1; x1 = rotl32(x1,13); x1 ^= x0;
    x0 += x1; x1 = rotl32(x1,15); x1 ^= x0;
    x0 += x1; x1 = rotl32(x1,26); x1 ^= x0;
    x0 += x1; x1 = rotl32(x1,6);  x1 ^= x0;
    x0 += k0; x1 += k1 + 3u;
    x0 += x1; x1 = rotl32(x1,17); x1 ^= x0;
    x0 += x1; x1 = rotl32(x1,29); x1 ^= x0;
    x0 += x1; x1 = rotl32(x1,16); x1 ^= x0;
    x0 += x1; x1 = rotl32(x1,24); x1 ^= x0;
    x0 += k1; x1 += ks2 + 4u;
    x0 += x1; x1 = rotl32(x1,13); x1 ^= x0;
    x0 += x1; x1 = rotl32(x1,15); x1 ^= x0;
    x0 += x1; x1 = rotl32(x1,26); x1 ^= x0;
    x0 += x1; x1 = rotl32(x1,6);  x1 ^= x0;
    x0 += ks2; x1 += k0 + 5u;
    return TFOut{x0, x1};
}

// jax.random.key(42) -> (0,42); partitionable split: kp=block(0,0), kn=block(0,1).
constexpr TFOut KP = threefry_full(0u, 42u, 0u, 0u);
constexpr TFOut KN = threefry_full(0u, 42u, 0u, 1u);

// Device-fast threefry: x0=0 implicit, keys compile-time, caller passes
// x1 pre-keyed (= f + K1). alignbit guarantees 1-inst rotates.
template<uint32_t TK0, uint32_t TK1>
__device__ __forceinline__ uint32_t tf_bits(uint32_t x1) {
    constexpr uint32_t KS2 = TK0 ^ TK1 ^ 0x1BD11BDAu;
    uint32_t x0 = TK0;
#define RND(r) x0 += x1; x1 = __builtin_amdgcn_alignbit(x1, x1, 32 - (r)); x1 ^= x0;
    RND(13) RND(15) RND(26) RND(6)
    x0 += TK1; x1 += KS2 + 1u;
    RND(17) RND(29) RND(16) RND(24)
    x0 += KS2; x1 += TK0 + 2u;
    RND(13) RND(15) RND(26) RND(6)
    x0 += TK0; x1 += TK1 + 3u;
    RND(17) RND(29) RND(16) RND(24)
    x0 += TK1; x1 += KS2 + 4u;
    RND(13) RND(15) RND(26) RND(6)
    x0 += KS2; x1 += TK0 + 5u;
#undef RND
    return x0 ^ x1;
}

__device__ __forceinline__ void mrg(uint32_t& H, uint32_t& J, uint32_t h2, uint32_t j2) {
    if (h2 > H || (h2 == H && j2 < J)) { H = h2; J = j2; }  // j tie: smaller wins
}

// Unchecked-zone scan: every element passes the predicate by construction.
// Unroll-4, preload next group (over-read past `end` stays inside d_ws).
template<uint32_t TK0, uint32_t TK1>
__device__ __forceinline__ void scan_main(const uint16_t* __restrict__ idx,
                                          int beg, int end, int lane,
                                          uint32_t kb, uint32_t& H, uint32_t& J)
{
    uint32_t h0 = 0, h1 = 0, h2 = 0, h3 = 0;
    uint32_t j0 = 0xFFFFFFFFu, j1 = 0xFFFFFFFFu, j2 = 0xFFFFFFFFu, j3 = 0xFFFFFFFFu;
    int s = beg;
    uint32_t a = 0, b = 0, c = 0, d = 0;
    if (s + 256 <= end) {
        a = idx[s + lane];       b = idx[s + lane + 64];
        c = idx[s + lane + 128]; d = idx[s + lane + 192];
    }
    while (s + 256 <= end) {
        const int sn = s + 256;
        const uint32_t na = idx[sn + lane];        // in flight across the 4 hashes
        const uint32_t nb = idx[sn + lane + 64];
        const uint32_t nc = idx[sn + lane + 128];
        const uint32_t nd = idx[sn + lane + 192];
        const uint32_t ha = tf_bits<TK0, TK1>(a + kb) >> 9;
        const uint32_t hb = tf_bits<TK0, TK1>(b + kb) >> 9;
        const uint32_t hc = tf_bits<TK0, TK1>(c + kb) >> 9;
        const uint32_t hd = tf_bits<TK0, TK1>(d + kb) >> 9;
        if (ha > h0) { h0 = ha; j0 = a; }
        if (hb > h1) { h1 = hb; j1 = b; }
        if (hc > h2) { h2 = hc; j2 = c; }
        if (hd > h3) { h3 = hd; j3 = d; }
        a = na; b = nb; c = nc; d = nd;
        s = sn;
    }
    for (int t = s + lane; t < end; t += 64) {
        const uint32_t j = idx[t];
        const uint32_t hh = tf_bits<TK0, TK1>(j + kb) >> 9;
        if (hh > h0) { h0 = hh; j0 = j; }
    }
    mrg(h0, j0, h1, j1); mrg(h2, j2, h3, j3); mrg(h0, j0, h2, j2);
    mrg(H, J, h0, j0);
}

// Boundary zone (~16 elems/row): exact fp32 predicate per element.
template<uint32_t TK0, uint32_t TK1, bool NEG>
__device__ __forceinline__ void scan_bnd(const float* __restrict__ st,
                                         const uint16_t* __restrict__ idx,
                                         int beg, int end, int lane, float ti,
                                         uint32_t kb, uint32_t& H, uint32_t& J,
                                         bool& found)
{
    for (int t = beg + lane; t < end; t += 64) {
        const float tj = st[t];
        const uint32_t j = idx[t];
        const uint32_t hh = tf_bits<TK0, TK1>(j + kb) >> 9;
        const float dd = ti - tj;
        const bool ok = NEG ? (dd > 0.1f) : (dd < -0.1f);
        if (ok) {
            found = true;
            if (hh > H || (hh == H && j < J)) { H = hh; J = j; }
        }
    }
}

// ------------- Kernel A: counting sort into K bins + accumulator init -------
__global__ __launch_bounds__(1024) void sort_kernel(
    const float* __restrict__ targets,
    float* __restrict__ sorted_t, uint16_t* __restrict__ sorted_idx,
    int* __restrict__ bin_start, float* __restrict__ loss_sum,
    float* __restrict__ valid_sum, unsigned int* __restrict__ done)
{
    __shared__ int hist[K];
    __shared__ int wsum[16];
    __shared__ int cursor[K];
    const int tid = threadIdx.x;

    hist[tid] = 0;
    if (tid == 0) { *loss_sum = 0.0f; *valid_sum = 0.0f; *done = 0u; }
    __syncthreads();

    float v[B / 1024];
    int   bnum[B / 1024];
    for (int i = 0; i < B / 1024; ++i) {
        const int e = tid + i * 1024;
        v[i] = targets[e];
        int b = (int)(v[i] * (float)K);
        b = b < 0 ? 0 : (b > K - 1 ? K - 1 : b);
        bnum[i] = b;
        atomicAdd(&hist[b], 1);
    }
    __syncthreads();

    const int cnt  = hist[tid];
    const int lane = tid & 63;
    const int wv   = tid >> 6;
    int incl = cnt;
    for (int d = 1; d < 64; d <<= 1) {
        const int o = __shfl_up(incl, d, 64);
        if (lane >= d) incl += o;
    }
    if (lane == 63) wsum[wv] = incl;
    __syncthreads();
    if (tid < 16) {
        int wincl = wsum[tid];
        for (int d = 1; d < 16; d <<= 1) {
            const int o = __shfl_up(wincl, d, 64);
            if (tid >= d) wincl += o;
        }
        wsum[tid] = wincl;
    }
    __syncthreads();
    incl += (wv > 0) ? wsum[wv - 1] : 0;
    bin_start[tid + 1] = incl;
    if (tid == 0) bin_start[0] = 0;
    cursor[tid] = incl - cnt;
    __syncthreads();

    for (int i = 0; i < B / 1024; ++i) {
        const int e = tid + i * 1024;
        const int p = atomicAdd(&cursor[bnum[i]], 1);
        sorted_t[p]   = v[i];
        sorted_idx[p] = (uint16_t)e;
    }
}

// ------------- Kernel B: per-wave row scan + fused finalize -----------------
__global__ __launch_bounds__(256) void rows_kernel(
    const float* __restrict__ preds, const float* __restrict__ targets,
    const float* __restrict__ sorted_t, const uint16_t* __restrict__ sorted_idx,
    const int* __restrict__ bin_start,
    float* __restrict__ loss_sum, float* __restrict__ valid_sum,
    unsigned int* __restrict__ done, float* __restrict__ out)
{
    __shared__ float sl[4], sv[4];
    const int lane = threadIdx.x & 63;
    const int wv   = threadIdx.x >> 6;
    const int row  = (blockIdx.x << 2) + wv;

    const float ti = targets[row];
    const uint32_t base = (uint32_t)row << 13;   // row * B

    // Candidate ranges from bins (identical construction to R3, bit-exact).
    const float cutn = ti - 0.1f;
    int bl = (int)floorf((cutn - 1e-4f) * (float)K);
    int bh = (int)floorf((cutn + 1e-4f) * (float)K) + 1;
    bl = bl < 0 ? 0 : (bl > K ? K : bl);
    bh = bh < 0 ? 0 : (bh > K ? K : bh);
    const int un_end = bin_start[bl];   // unchecked neg: [0, un_end)
    const int cn_end = bin_start[bh];   // checked  neg: [un_end, cn_end)

    const float cutp = ti + 0.1f;
    int pl = (int)floorf((cutp - 1e-4f) * (float)K);
    int ph = (int)floorf((cutp + 1e-4f) * (float)K) + 1;
    pl = pl < 0 ? 0 : (pl > K ? K : pl);
    ph = ph < 0 ? 0 : (ph > K ? K : ph);
    const int cp_beg = bin_start[pl];   // checked  pos: [cp_beg, up_beg)
    const int up_beg = bin_start[ph];   // unchecked pos: [up_beg, B)

    uint32_t Hn = 0, Jn = 0xFFFFFFFFu;
    bool fn = false;
    scan_main<KN.a, KN.b>(sorted_idx, 0, un_end, lane, base + KN.b, Hn, Jn);
    scan_bnd<KN.a, KN.b, true>(sorted_t, sorted_idx, un_end, cn_end, lane, ti,
                               base + KN.b, Hn, Jn, fn);
    const bool valid_n = (un_end > 0) || __any(fn);

    uint32_t Hp = 0, Jp = 0xFFFFFFFFu;
    bool fp2 = false;
    scan_main<KP.a, KP.b>(sorted_idx, up_beg, B, lane, base + KP.b, Hp, Jp);
    scan_bnd<KP.a, KP.b, false>(sorted_t, sorted_idx, cp_beg, up_beg, lane, ti,
                                base + KP.b, Hp, Jp, fp2);
    const bool valid_p = (up_beg < B) || __any(fp2);

    // In-wave (h, j) max-reduction with first-index tie-break.
    for (int off = 32; off > 0; off >>= 1) {
        const uint32_t ohn = __shfl_down(Hn, off, 64);
        const uint32_t ojn = __shfl_down(Jn, off, 64);
        if (ohn > Hn || (ohn == Hn && ojn < Jn)) { Hn = ohn; Jn = ojn; }
        const uint32_t ohp = __shfl_down(Hp, off, 64);
        const uint32_t ojp = __shfl_down(Jp, off, 64);
        if (ohp > Hp || (ohp == Hp && ojp < Jp)) { Hp = ohp; Jp = ojp; }
    }

    if (lane == 0) {
        float loss = 0.0f, valid = 0.0f;
        if (valid_n && valid_p) {
            const float per = 0.5f - (preds[Jp & 8191u] - preds[Jn & 8191u]);
            loss = per > 0.0f ? per : 0.0f;
            valid = 1.0f;
        }
        sl[wv] = loss; sv[wv] = valid;
    }
    __syncthreads();
    if (threadIdx.x == 0) {
        atomicAdd(loss_sum,  sl[0] + sl[1] + sl[2] + sl[3]);
        atomicAdd(valid_sum, sv[0] + sv[1] + sv[2] + sv[3]);
        __threadfence();
        const unsigned int old = atomicAdd(done, 1u);
        if (old == gridDim.x - 1u) {          // last block finalizes
            const float ls = atomicAdd(loss_sum, 0.0f);
            const float vs = atomicAdd(valid_sum, 0.0f);
            out[0] = vs > 0.0f ? ls / fmaxf(vs, 1.0f) : 0.0f;
        }
    }
}

extern "C" void kernel_launch(void* const* d_in, const int* in_sizes, int n_in,
                              void* d_out, int out_size, void* d_ws, size_t ws_size,
                              hipStream_t stream) {
    const float* preds   = (const float*)d_in[0];
    const float* targets = (const float*)d_in[1];

    float* ws = (float*)d_ws;
    float*        sorted_t   = ws;                       // B floats
    uint16_t*     sorted_idx = (uint16_t*)(ws + B);      // B u16 (+512B over-read slack follows)
    int*          bin_start  = (int*)(ws + B + B / 2 + 256); // K+1 ints, after slack
    float*        loss_sum   = ws + B + B / 2 + 2048;
    float*        valid_sum  = loss_sum + 1;
    unsigned int* done       = (unsigned int*)(loss_sum + 2);

    sort_kernel<<<1, 1024, 0, stream>>>(targets, sorted_t, sorted_idx, bin_start,
                                        loss_sum, valid_sum, done);
    rows_kernel<<<B / 4, 256, 0, stream>>>(preds, targets, sorted_t, sorted_idx,
                                           bin_start, loss_sum, valid_sum, done,
                                           (float*)d_out);
}